// Round 1
// baseline (374.933 us; speedup 1.0000x reference)
//
#include <hip/hip_runtime.h>
#include <hip/hip_bf16.h>

#define N_NODES 10000
#define N_EDGES 640000
#define D 128
#define N_LAYERS 4

// ---------------- CSR build ----------------

__global__ void zero_kernel(int* __restrict__ p, int n) {
    int i = blockIdx.x * 256 + threadIdx.x;
    if (i < n) p[i] = 0;
}

__global__ void hist_kernel(const int* __restrict__ dst, int* __restrict__ deg) {
    int e = blockIdx.x * 256 + threadIdx.x;
    if (e < N_EDGES) atomicAdd(&deg[dst[e]], 1);
}

// single-block scan over 10000 degrees -> rowptr (exclusive boundaries) + cursor copy
__global__ __launch_bounds__(1024) void scan_kernel(const int* __restrict__ deg,
                                                    int* __restrict__ rowptr,
                                                    int* __restrict__ cursor) {
    __shared__ int buf[1024];
    __shared__ int carry_s;
    int tid = threadIdx.x;
    if (tid == 0) { carry_s = 0; rowptr[0] = 0; }
    __syncthreads();
    for (int base = 0; base < N_NODES; base += 1024) {
        int i = base + tid;
        int v = (i < N_NODES) ? deg[i] : 0;
        buf[tid] = v;
        __syncthreads();
        // Hillis-Steele inclusive scan
        for (int off = 1; off < 1024; off <<= 1) {
            int t = (tid >= off) ? buf[tid - off] : 0;
            __syncthreads();
            buf[tid] += t;
            __syncthreads();
        }
        int incl = buf[tid] + carry_s;
        if (i < N_NODES) {
            rowptr[i + 1] = incl;
            cursor[i] = incl - v;   // exclusive prefix = write cursor start
        }
        __syncthreads();
        if (tid == 1023) carry_s = incl;
        __syncthreads();
    }
}

__global__ void scatter_kernel(const int* __restrict__ src, const int* __restrict__ dst,
                               int* __restrict__ cursor, int* __restrict__ csr) {
    int e = blockIdx.x * 256 + threadIdx.x;
    if (e < N_EDGES) {
        int pos = atomicAdd(&cursor[dst[e]], 1);
        csr[pos] = src[e];
    }
}

// ---------------- per-layer kernels ----------------

// hl = h @ W + b  (fp32, W staged in LDS; block = 64 rows x 128 cols; thread = 4 rows x 8 cols)
__global__ __launch_bounds__(256) void gemm_kernel(const float* __restrict__ h,
                                                   const float* __restrict__ W,
                                                   const float* __restrict__ bias,
                                                   float* __restrict__ hl) {
    __shared__ float Ws[D * D];
    __shared__ float bs_s[D];
    // cooperative load of W (16384 floats) as float4
    const float4* Wv = (const float4*)W;
    float4* Wsv = (float4*)Ws;
    for (int i = threadIdx.x; i < D * D / 4; i += 256) Wsv[i] = Wv[i];
    if (threadIdx.x < D) bs_s[threadIdx.x] = bias[threadIdx.x];
    __syncthreads();

    const int rg = threadIdx.x >> 4;   // 0..15 row-groups (4 rows each)
    const int cg = threadIdx.x & 15;   // 0..15 col-groups (8 cols each)
    const int row0 = blockIdx.x * 64 + rg * 4;
    const int col0 = cg * 8;

    float acc[4][8];
#pragma unroll
    for (int r = 0; r < 4; ++r)
#pragma unroll
        for (int c = 0; c < 8; ++c) acc[r][c] = 0.f;

    for (int k = 0; k < D; k += 4) {
        float a[4][4];
#pragma unroll
        for (int r = 0; r < 4; ++r) {
            int rr = row0 + r;
            if (rr > N_NODES - 1) rr = N_NODES - 1;   // clamp for OOB-safe load
            float4 t = *(const float4*)(h + rr * D + k);
            a[r][0] = t.x; a[r][1] = t.y; a[r][2] = t.z; a[r][3] = t.w;
        }
#pragma unroll
        for (int kk = 0; kk < 4; ++kk) {
            float4 w0 = *(const float4*)(&Ws[(k + kk) * D + col0]);
            float4 w1 = *(const float4*)(&Ws[(k + kk) * D + col0 + 4]);
#pragma unroll
            for (int r = 0; r < 4; ++r) {
                float av = a[r][kk];
                acc[r][0] += av * w0.x; acc[r][1] += av * w0.y;
                acc[r][2] += av * w0.z; acc[r][3] += av * w0.w;
                acc[r][4] += av * w1.x; acc[r][5] += av * w1.y;
                acc[r][6] += av * w1.z; acc[r][7] += av * w1.w;
            }
        }
    }

#pragma unroll
    for (int r = 0; r < 4; ++r) {
        int rr = row0 + r;
        if (rr < N_NODES) {
            float4 o0, o1;
            o0.x = acc[r][0] + bs_s[col0 + 0];
            o0.y = acc[r][1] + bs_s[col0 + 1];
            o0.z = acc[r][2] + bs_s[col0 + 2];
            o0.w = acc[r][3] + bs_s[col0 + 3];
            o1.x = acc[r][4] + bs_s[col0 + 4];
            o1.y = acc[r][5] + bs_s[col0 + 5];
            o1.z = acc[r][6] + bs_s[col0 + 6];
            o1.w = acc[r][7] + bs_s[col0 + 7];
            *(float4*)(hl + rr * D + col0) = o0;
            *(float4*)(hl + rr * D + col0 + 4) = o1;
        }
    }
}

// out[v] = relu(hl[v] + sum_{e in-edges of v} hl[src[e]])
// one wave (64 lanes) per node, lane handles 2 consecutive floats (float2)
__global__ __launch_bounds__(256) void aggregate_kernel(const float* __restrict__ hl,
                                                        const int* __restrict__ rowptr,
                                                        const int* __restrict__ csr,
                                                        float* __restrict__ out) {
    int node = blockIdx.x * 4 + (threadIdx.x >> 6);
    if (node >= N_NODES) return;
    int lane = threadIdx.x & 63;

    int beg = rowptr[node];
    int end = rowptr[node + 1];

    float2 acc = ((const float2*)(hl + node * D))[lane];   // self loop

    int e = beg;
    for (; e + 4 <= end; e += 4) {
        int u0 = csr[e + 0];
        int u1 = csr[e + 1];
        int u2 = csr[e + 2];
        int u3 = csr[e + 3];
        float2 v0 = ((const float2*)(hl + u0 * D))[lane];
        float2 v1 = ((const float2*)(hl + u1 * D))[lane];
        float2 v2 = ((const float2*)(hl + u2 * D))[lane];
        float2 v3 = ((const float2*)(hl + u3 * D))[lane];
        acc.x += (v0.x + v1.x) + (v2.x + v3.x);
        acc.y += (v0.y + v1.y) + (v2.y + v3.y);
    }
    for (; e < end; ++e) {
        int u = csr[e];
        float2 v = ((const float2*)(hl + u * D))[lane];
        acc.x += v.x;
        acc.y += v.y;
    }

    float2 r;
    r.x = fmaxf(acc.x, 0.f);
    r.y = fmaxf(acc.y, 0.f);
    ((float2*)(out + node * D))[lane] = r;
}

// ---------------- launch ----------------

extern "C" void kernel_launch(void* const* d_in, const int* in_sizes, int n_in,
                              void* d_out, int out_size, void* d_ws, size_t ws_size,
                              hipStream_t stream) {
    const float* node_feats = (const float*)d_in[0];
    const int*   src        = (const int*)d_in[1];
    const int*   dst        = (const int*)d_in[2];
    const float* Ws         = (const float*)d_in[3];
    const float* bs         = (const float*)d_in[4];
    float* out = (float*)d_out;

    char* ws = (char*)d_ws;
    int*   deg    = (int*)(ws + 0);            //  10000 ints
    int*   rowptr = (int*)(ws + 40960);        //  10001 ints
    int*   cursor = (int*)(ws + 81920);        //  10000 ints
    int*   csr    = (int*)(ws + 122880);       // 640000 ints
    float* hl     = (float*)(ws + 2682880);    // 10000*128 floats
    float* bufA   = (float*)(ws + 7802880);    // 10000*128 floats
    // total: ~12.9 MB

    // CSR build (every call; ws is re-poisoned by harness)
    zero_kernel<<<(N_NODES + 255) / 256, 256, 0, stream>>>(deg, N_NODES);
    hist_kernel<<<(N_EDGES + 255) / 256, 256, 0, stream>>>(dst, deg);
    scan_kernel<<<1, 1024, 0, stream>>>(deg, rowptr, cursor);
    scatter_kernel<<<(N_EDGES + 255) / 256, 256, 0, stream>>>(src, dst, cursor, csr);

    const float* hin = node_feats;
    for (int l = 0; l < N_LAYERS; ++l) {
        gemm_kernel<<<(N_NODES + 63) / 64, 256, 0, stream>>>(
            hin, Ws + (size_t)l * D * D, bs + (size_t)l * D, hl);
        float* hout = (l % 2 == 0) ? bufA : out;   // L0->bufA, L1->out, L2->bufA, L3->out
        aggregate_kernel<<<(N_NODES + 3) / 4, 256, 0, stream>>>(hl, rowptr, csr, hout);
        hin = hout;
    }
}

// Round 3
// 302.310 us; speedup vs baseline: 1.2402x; 1.2402x over previous
//
#include <hip/hip_runtime.h>
#include <hip/hip_bf16.h>

#define N_NODES 10000
#define N_EDGES 640000
#define D 128
#define N_LAYERS 4

// ---------------- CSR build ----------------

__global__ void zero_kernel(int* __restrict__ p, int n) {
    int i = blockIdx.x * 256 + threadIdx.x;
    if (i < n) p[i] = 0;
}

__global__ void hist_kernel(const int* __restrict__ dst, int* __restrict__ deg) {
    int e = blockIdx.x * 256 + threadIdx.x;
    if (e < N_EDGES) atomicAdd(&deg[dst[e]], 1);
}

// shuffle-based scan: 1024 threads x 10 elements each covers 10240 >= N_NODES
__global__ __launch_bounds__(1024) void scan_kernel(const int* __restrict__ deg,
                                                    int* __restrict__ rowptr,
                                                    int* __restrict__ cursor) {
    __shared__ int waveTot[16];
    const int tid = threadIdx.x;
    const int lane = tid & 63;
    const int wave = tid >> 6;
    const int base = tid * 10;

    int d[10];
    int run = 0;
#pragma unroll
    for (int j = 0; j < 10; ++j) {
        int i = base + j;
        int v = (i < N_NODES) ? deg[i] : 0;
        d[j] = v;
        run += v;
    }
    // wave-level inclusive scan of per-thread totals
    int x = run;
#pragma unroll
    for (int off = 1; off < 64; off <<= 1) {
        int t = __shfl_up(x, off);
        if (lane >= off) x += t;
    }
    if (lane == 63) waveTot[wave] = x;
    __syncthreads();
    if (wave == 0) {
        int w = (lane < 16) ? waveTot[lane] : 0;
#pragma unroll
        for (int off = 1; off < 16; off <<= 1) {
            int t = __shfl_up(w, off);
            if (lane >= off) w += t;
        }
        if (lane < 16) waveTot[lane] = w;   // inclusive wave totals
    }
    __syncthreads();
    int waveExcl = (wave == 0) ? 0 : waveTot[wave - 1];
    int s = waveExcl + (x - run);           // thread-exclusive prefix
#pragma unroll
    for (int j = 0; j < 10; ++j) {
        int i = base + j;
        if (i < N_NODES) {
            cursor[i] = s;
            s += d[j];
            rowptr[i + 1] = s;
        }
    }
    if (tid == 0) rowptr[0] = 0;
}

__global__ void scatter_kernel(const int* __restrict__ src, const int* __restrict__ dst,
                               int* __restrict__ cursor, int* __restrict__ csr) {
    int e = blockIdx.x * 256 + threadIdx.x;
    if (e < N_EDGES) {
        int pos = atomicAdd(&cursor[dst[e]], 1);
        csr[pos] = src[e];
    }
}

// ---------------- per-layer kernels ----------------

// hl(bf16) = h(fp32) @ W + b  (fp32 math, W staged in LDS)
__global__ __launch_bounds__(256) void gemm_kernel(const float* __restrict__ h,
                                                   const float* __restrict__ W,
                                                   const float* __restrict__ bias,
                                                   __hip_bfloat16* __restrict__ hl) {
    __shared__ float Ws[D * D];
    __shared__ float bs_s[D];
    const float4* Wv = (const float4*)W;
    float4* Wsv = (float4*)Ws;
    for (int i = threadIdx.x; i < D * D / 4; i += 256) Wsv[i] = Wv[i];
    if (threadIdx.x < D) bs_s[threadIdx.x] = bias[threadIdx.x];
    __syncthreads();

    const int rg = threadIdx.x >> 4;
    const int cg = threadIdx.x & 15;
    const int row0 = blockIdx.x * 64 + rg * 4;
    const int col0 = cg * 8;

    float acc[4][8];
#pragma unroll
    for (int r = 0; r < 4; ++r)
#pragma unroll
        for (int c = 0; c < 8; ++c) acc[r][c] = 0.f;

    for (int k = 0; k < D; k += 4) {
        float a[4][4];
#pragma unroll
        for (int r = 0; r < 4; ++r) {
            int rr = row0 + r;
            if (rr > N_NODES - 1) rr = N_NODES - 1;
            float4 t = *(const float4*)(h + rr * D + k);
            a[r][0] = t.x; a[r][1] = t.y; a[r][2] = t.z; a[r][3] = t.w;
        }
#pragma unroll
        for (int kk = 0; kk < 4; ++kk) {
            float4 w0 = *(const float4*)(&Ws[(k + kk) * D + col0]);
            float4 w1 = *(const float4*)(&Ws[(k + kk) * D + col0 + 4]);
#pragma unroll
            for (int r = 0; r < 4; ++r) {
                float av = a[r][kk];
                acc[r][0] += av * w0.x; acc[r][1] += av * w0.y;
                acc[r][2] += av * w0.z; acc[r][3] += av * w0.w;
                acc[r][4] += av * w1.x; acc[r][5] += av * w1.y;
                acc[r][6] += av * w1.z; acc[r][7] += av * w1.w;
            }
        }
    }

#pragma unroll
    for (int r = 0; r < 4; ++r) {
        int rr = row0 + r;
        if (rr < N_NODES) {
            union { uint4 u; __hip_bfloat16 b[8]; } o;   // 8 bf16 = 16 bytes = uint4
#pragma unroll
            for (int c = 0; c < 8; ++c)
                o.b[c] = __float2bfloat16(acc[r][c] + bs_s[col0 + c]);
            *(uint4*)((unsigned short*)hl + rr * D + col0) = o.u;
        }
    }
}

__device__ __forceinline__ float bf_lo(unsigned u) {
    u <<= 16; return __builtin_bit_cast(float, u);
}
__device__ __forceinline__ float bf_hi(unsigned u) {
    u &= 0xffff0000u; return __builtin_bit_cast(float, u);
}

// out[v] = relu(hl[v] + sum_{in-edges} hl[src]); hl in bf16 (row = 64 dwords), out fp32
__global__ __launch_bounds__(256) void aggregate_kernel(const unsigned* __restrict__ hlu,
                                                        const int* __restrict__ rowptr,
                                                        const int* __restrict__ csr,
                                                        float* __restrict__ out) {
    int node = blockIdx.x * 4 + (threadIdx.x >> 6);
    if (node >= N_NODES) return;
    int lane = threadIdx.x & 63;

    int beg = rowptr[node];
    int end = rowptr[node + 1];

    unsigned su = hlu[node * 64 + lane];     // self loop
    float ax = bf_lo(su), ay = bf_hi(su);

    int e = beg;
    for (; e + 4 <= end; e += 4) {
        int u0 = csr[e + 0];
        int u1 = csr[e + 1];
        int u2 = csr[e + 2];
        int u3 = csr[e + 3];
        unsigned v0 = hlu[u0 * 64 + lane];
        unsigned v1 = hlu[u1 * 64 + lane];
        unsigned v2 = hlu[u2 * 64 + lane];
        unsigned v3 = hlu[u3 * 64 + lane];
        ax += (bf_lo(v0) + bf_lo(v1)) + (bf_lo(v2) + bf_lo(v3));
        ay += (bf_hi(v0) + bf_hi(v1)) + (bf_hi(v2) + bf_hi(v3));
    }
    for (; e < end; ++e) {
        unsigned v = hlu[csr[e] * 64 + lane];
        ax += bf_lo(v);
        ay += bf_hi(v);
    }

    float2 r;
    r.x = fmaxf(ax, 0.f);
    r.y = fmaxf(ay, 0.f);
    ((float2*)(out + node * D))[lane] = r;
}

// ---------------- launch ----------------

extern "C" void kernel_launch(void* const* d_in, const int* in_sizes, int n_in,
                              void* d_out, int out_size, void* d_ws, size_t ws_size,
                              hipStream_t stream) {
    const float* node_feats = (const float*)d_in[0];
    const int*   src        = (const int*)d_in[1];
    const int*   dst        = (const int*)d_in[2];
    const float* Ws         = (const float*)d_in[3];
    const float* bs         = (const float*)d_in[4];
    float* out = (float*)d_out;

    char* ws = (char*)d_ws;
    int*   deg    = (int*)(ws + 0);            //  10000 ints
    int*   rowptr = (int*)(ws + 40960);        //  10001 ints
    int*   cursor = (int*)(ws + 81920);        //  10000 ints
    int*   csr    = (int*)(ws + 122880);       // 640000 ints  -> ends 2682880
    __hip_bfloat16* hl = (__hip_bfloat16*)(ws + 2682880);   // 10000*128 bf16 (2.56 MB) -> ends 5242880
    float* bufA   = (float*)(ws + 5242880);    // 10000*128 fp32 (5.12 MB)

    zero_kernel<<<(N_NODES + 255) / 256, 256, 0, stream>>>(deg, N_NODES);
    hist_kernel<<<(N_EDGES + 255) / 256, 256, 0, stream>>>(dst, deg);
    scan_kernel<<<1, 1024, 0, stream>>>(deg, rowptr, cursor);
    scatter_kernel<<<(N_EDGES + 255) / 256, 256, 0, stream>>>(src, dst, cursor, csr);

    const float* hin = node_feats;
    for (int l = 0; l < N_LAYERS; ++l) {
        gemm_kernel<<<(N_NODES + 63) / 64, 256, 0, stream>>>(
            hin, Ws + (size_t)l * D * D, bs + (size_t)l * D, hl);
        float* hout = (l % 2 == 0) ? bufA : out;
        aggregate_kernel<<<(N_NODES + 3) / 4, 256, 0, stream>>>(
            (const unsigned*)hl, rowptr, csr, hout);
        hin = hout;
    }
}

// Round 4
// 235.160 us; speedup vs baseline: 1.5944x; 1.2855x over previous
//
#include <hip/hip_runtime.h>
#include <hip/hip_bf16.h>

#define N_NODES 10000
#define N_EDGES 640000
#define D 128
#define N_LAYERS 4

#define NBINS 79          // ceil(10000/128) coarse bins of 128 consecutive dst
#define BIN_CAP 10240     // per-bin capacity (mean 8192, sigma ~90 -> 22 sigma margin)

// ---------------- CSR build (2-phase counting sort) ----------------

__global__ void zero_small_kernel(int* __restrict__ p, int n) {
    int i = threadIdx.x;
    if (i < n) p[i] = 0;
}

// Phase A: bin edges by dst>>7 into per-bin contiguous runs.
// key = (dst<<14)|src  (both < 16384)
__global__ __launch_bounds__(256) void binA_kernel(const int* __restrict__ src,
                                                   const int* __restrict__ dst,
                                                   int* __restrict__ binCursor,
                                                   unsigned* __restrict__ binbuf) {
    __shared__ int cnt[NBINS];
    __shared__ int gbase[NBINS];
    const int t = threadIdx.x;
    if (t < NBINS) cnt[t] = 0;
    __syncthreads();

    const int e0 = blockIdx.x * 2560;   // 250 blocks * 2560 = 640000 exactly
    unsigned key[10];
    int bin[10], pos[10];
#pragma unroll
    for (int j = 0; j < 10; ++j) {
        int e = e0 + j * 256 + t;
        int d = dst[e];
        int s = src[e];
        key[j] = ((unsigned)d << 14) | (unsigned)s;
        bin[j] = d >> 7;
        pos[j] = atomicAdd(&cnt[bin[j]], 1);
    }
    __syncthreads();
    if (t < NBINS) gbase[t] = atomicAdd(&binCursor[t], cnt[t]);
    __syncthreads();
#pragma unroll
    for (int j = 0; j < 10; ++j) {
        int p = gbase[bin[j]] + pos[j];
        if (p < BIN_CAP) binbuf[bin[j] * BIN_CAP + p] = key[j];
    }
}

// Phase B: per bin, sub-sort by node; write csr IN PLACE over binbuf
// (block-private region -> each HBM line written back once).
// Emits begs[v], degs[v].
__global__ __launch_bounds__(256) void binB_kernel(unsigned* __restrict__ binbuf,
                                                   const int* __restrict__ binCursor,
                                                   int* __restrict__ begs,
                                                   int* __restrict__ degs) {
    __shared__ unsigned buf[BIN_CAP];
    __shared__ int deg[128], base[128], cur[128];
    const int b = blockIdx.x;
    const int t = threadIdx.x;
    int m = binCursor[b];
    if (m > BIN_CAP) m = BIN_CAP;

    if (t < 128) deg[t] = 0;
    __syncthreads();

    for (int i = t; i < m; i += 256) {
        unsigned k = binbuf[(size_t)b * BIN_CAP + i];
        buf[i] = k;
        atomicAdd(&deg[(k >> 14) & 127], 1);
    }
    __syncthreads();

    // exclusive scan of deg[128] by wave 0 (lane handles 2 elements)
    if (t < 64) {
        int a0 = deg[2 * t], a1 = deg[2 * t + 1];
        int s = a0 + a1;
        int x = s;
#pragma unroll
        for (int off = 1; off < 64; off <<= 1) {
            int tt = __shfl_up(x, off);
            if (t >= off) x += tt;
        }
        base[2 * t]     = x - s;
        base[2 * t + 1] = x - a1;
        cur[2 * t]      = x - s;
        cur[2 * t + 1]  = x - a1;
    }
    __syncthreads();

    if (t < 128) {
        int v = b * 128 + t;
        if (v < N_NODES) {
            degs[v] = deg[t];
            begs[v] = b * BIN_CAP + base[t];
        }
    }

    for (int i = t; i < m; i += 256) {
        unsigned k = buf[i];
        int p = atomicAdd(&cur[(k >> 14) & 127], 1);
        binbuf[(size_t)b * BIN_CAP + p] = k & 0x3FFFu;   // store src only
    }
}

// ---------------- per-layer kernels ----------------

// hl(bf16) = h(fp32) @ W + b  (fp32 math, W staged in LDS)
__global__ __launch_bounds__(256) void gemm_kernel(const float* __restrict__ h,
                                                   const float* __restrict__ W,
                                                   const float* __restrict__ bias,
                                                   __hip_bfloat16* __restrict__ hl) {
    __shared__ float Ws[D * D];
    __shared__ float bs_s[D];
    const float4* Wv = (const float4*)W;
    float4* Wsv = (float4*)Ws;
    for (int i = threadIdx.x; i < D * D / 4; i += 256) Wsv[i] = Wv[i];
    if (threadIdx.x < D) bs_s[threadIdx.x] = bias[threadIdx.x];
    __syncthreads();

    const int rg = threadIdx.x >> 4;
    const int cg = threadIdx.x & 15;
    const int row0 = blockIdx.x * 64 + rg * 4;
    const int col0 = cg * 8;

    float acc[4][8];
#pragma unroll
    for (int r = 0; r < 4; ++r)
#pragma unroll
        for (int c = 0; c < 8; ++c) acc[r][c] = 0.f;

    for (int k = 0; k < D; k += 4) {
        float a[4][4];
#pragma unroll
        for (int r = 0; r < 4; ++r) {
            int rr = row0 + r;
            if (rr > N_NODES - 1) rr = N_NODES - 1;
            float4 t = *(const float4*)(h + rr * D + k);
            a[r][0] = t.x; a[r][1] = t.y; a[r][2] = t.z; a[r][3] = t.w;
        }
#pragma unroll
        for (int kk = 0; kk < 4; ++kk) {
            float4 w0 = *(const float4*)(&Ws[(k + kk) * D + col0]);
            float4 w1 = *(const float4*)(&Ws[(k + kk) * D + col0 + 4]);
#pragma unroll
            for (int r = 0; r < 4; ++r) {
                float av = a[r][kk];
                acc[r][0] += av * w0.x; acc[r][1] += av * w0.y;
                acc[r][2] += av * w0.z; acc[r][3] += av * w0.w;
                acc[r][4] += av * w1.x; acc[r][5] += av * w1.y;
                acc[r][6] += av * w1.z; acc[r][7] += av * w1.w;
            }
        }
    }

#pragma unroll
    for (int r = 0; r < 4; ++r) {
        int rr = row0 + r;
        if (rr < N_NODES) {
            union { uint4 u; __hip_bfloat16 b[8]; } o;
#pragma unroll
            for (int c = 0; c < 8; ++c)
                o.b[c] = __float2bfloat16(acc[r][c] + bs_s[col0 + c]);
            *(uint4*)((unsigned short*)hl + rr * D + col0) = o.u;
        }
    }
}

__device__ __forceinline__ float bf_lo(unsigned u) {
    u <<= 16; return __builtin_bit_cast(float, u);
}
__device__ __forceinline__ float bf_hi(unsigned u) {
    u &= 0xffff0000u; return __builtin_bit_cast(float, u);
}

// out[v] = relu(hl[v] + sum_{in-edges} hl[src]); hl bf16 (row = 64 dwords), out fp32
__global__ __launch_bounds__(256) void aggregate_kernel(const unsigned* __restrict__ hlu,
                                                        const int* __restrict__ begs,
                                                        const int* __restrict__ degs,
                                                        const int* __restrict__ csr,
                                                        float* __restrict__ out) {
    int node = blockIdx.x * 4 + (threadIdx.x >> 6);
    if (node >= N_NODES) return;
    int lane = threadIdx.x & 63;

    int beg = begs[node];
    int end = beg + degs[node];

    unsigned su = hlu[node * 64 + lane];     // self loop
    float ax = bf_lo(su), ay = bf_hi(su);

    int e = beg;
    for (; e + 4 <= end; e += 4) {
        int u0 = csr[e + 0];
        int u1 = csr[e + 1];
        int u2 = csr[e + 2];
        int u3 = csr[e + 3];
        unsigned v0 = hlu[u0 * 64 + lane];
        unsigned v1 = hlu[u1 * 64 + lane];
        unsigned v2 = hlu[u2 * 64 + lane];
        unsigned v3 = hlu[u3 * 64 + lane];
        ax += (bf_lo(v0) + bf_lo(v1)) + (bf_lo(v2) + bf_lo(v3));
        ay += (bf_hi(v0) + bf_hi(v1)) + (bf_hi(v2) + bf_hi(v3));
    }
    for (; e < end; ++e) {
        unsigned v = hlu[csr[e] * 64 + lane];
        ax += bf_lo(v);
        ay += bf_hi(v);
    }

    float2 r;
    r.x = fmaxf(ax, 0.f);
    r.y = fmaxf(ay, 0.f);
    ((float2*)(out + node * D))[lane] = r;
}

// ---------------- launch ----------------

extern "C" void kernel_launch(void* const* d_in, const int* in_sizes, int n_in,
                              void* d_out, int out_size, void* d_ws, size_t ws_size,
                              hipStream_t stream) {
    const float* node_feats = (const float*)d_in[0];
    const int*   src        = (const int*)d_in[1];
    const int*   dst        = (const int*)d_in[2];
    const float* Ws         = (const float*)d_in[3];
    const float* bs         = (const float*)d_in[4];
    float* out = (float*)d_out;

    char* ws = (char*)d_ws;
    int*      binCursor = (int*)(ws + 0);          // 79 ints
    int*      begs      = (int*)(ws + 1024);       // 10240 ints -> ends 41984
    int*      degs      = (int*)(ws + 41984);      // 10240 ints -> ends 82944
    unsigned* binbuf    = (unsigned*)(ws + 82944); // 79*10240 u32 = 3235840 B -> ends 3318784 (csr in place)
    __hip_bfloat16* hl  = (__hip_bfloat16*)(ws + 3318784); // 2.56 MB -> ends 5878784
    float*    bufA      = (float*)(ws + 5878784);  // 5.12 MB -> ends 10998784 (~11 MB)

    zero_small_kernel<<<1, 128, 0, stream>>>(binCursor, NBINS);
    binA_kernel<<<250, 256, 0, stream>>>(src, dst, binCursor, binbuf);
    binB_kernel<<<NBINS, 256, 0, stream>>>(binbuf, binCursor, begs, degs);

    const float* hin = node_feats;
    for (int l = 0; l < N_LAYERS; ++l) {
        gemm_kernel<<<(N_NODES + 63) / 64, 256, 0, stream>>>(
            hin, Ws + (size_t)l * D * D, bs + (size_t)l * D, hl);
        float* hout = (l % 2 == 0) ? bufA : out;
        aggregate_kernel<<<(N_NODES + 3) / 4, 256, 0, stream>>>(
            (const unsigned*)hl, begs, degs, (const int*)binbuf, hout);
        hin = hout;
    }
}

// Round 5
// 232.719 us; speedup vs baseline: 1.6111x; 1.0105x over previous
//
#include <hip/hip_runtime.h>
#include <hip/hip_bf16.h>

#define N_NODES 10000
#define N_EDGES 640000
#define D 128
#define N_LAYERS 4

#define NBINS 79          // ceil(10000/128) coarse bins of 128 consecutive dst
#define BIN_CAP 10240     // per-bin capacity (mean 8192, sigma ~90 -> 22 sigma margin)

// ---------------- CSR build (2-phase counting sort) ----------------

__global__ void zero_small_kernel(int* __restrict__ p, int n) {
    int i = threadIdx.x;
    if (i < n) p[i] = 0;
}

// Phase A: bin edges by dst>>7 into per-bin contiguous runs.
// key = (dst<<14)|src  (both < 16384)
__global__ __launch_bounds__(256) void binA_kernel(const int* __restrict__ src,
                                                   const int* __restrict__ dst,
                                                   int* __restrict__ binCursor,
                                                   unsigned* __restrict__ binbuf) {
    __shared__ int cnt[NBINS];
    __shared__ int gbase[NBINS];
    const int t = threadIdx.x;
    if (t < NBINS) cnt[t] = 0;
    __syncthreads();

    const int e0 = blockIdx.x * 2560;   // 250 blocks * 2560 = 640000 exactly
    unsigned key[10];
    int bin[10], pos[10];
#pragma unroll
    for (int j = 0; j < 10; ++j) {
        int e = e0 + j * 256 + t;
        int d = dst[e];
        int s = src[e];
        key[j] = ((unsigned)d << 14) | (unsigned)s;
        bin[j] = d >> 7;
        pos[j] = atomicAdd(&cnt[bin[j]], 1);
    }
    __syncthreads();
    if (t < NBINS) gbase[t] = atomicAdd(&binCursor[t], cnt[t]);
    __syncthreads();
#pragma unroll
    for (int j = 0; j < 10; ++j) {
        int p = gbase[bin[j]] + pos[j];
        if (p < BIN_CAP) binbuf[bin[j] * BIN_CAP + p] = key[j];
    }
}

// Phase B: per bin, sub-sort by node; write csr IN PLACE over binbuf.
// Emits begs[v], degs[v].
__global__ __launch_bounds__(256) void binB_kernel(unsigned* __restrict__ binbuf,
                                                   const int* __restrict__ binCursor,
                                                   int* __restrict__ begs,
                                                   int* __restrict__ degs) {
    __shared__ unsigned buf[BIN_CAP];
    __shared__ int deg[128], base[128], cur[128];
    const int b = blockIdx.x;
    const int t = threadIdx.x;
    int m = binCursor[b];
    if (m > BIN_CAP) m = BIN_CAP;

    if (t < 128) deg[t] = 0;
    __syncthreads();

    for (int i = t; i < m; i += 256) {
        unsigned k = binbuf[(size_t)b * BIN_CAP + i];
        buf[i] = k;
        atomicAdd(&deg[(k >> 14) & 127], 1);
    }
    __syncthreads();

    if (t < 64) {
        int a0 = deg[2 * t], a1 = deg[2 * t + 1];
        int s = a0 + a1;
        int x = s;
#pragma unroll
        for (int off = 1; off < 64; off <<= 1) {
            int tt = __shfl_up(x, off);
            if (t >= off) x += tt;
        }
        base[2 * t]     = x - s;
        base[2 * t + 1] = x - a1;
        cur[2 * t]      = x - s;
        cur[2 * t + 1]  = x - a1;
    }
    __syncthreads();

    if (t < 128) {
        int v = b * 128 + t;
        if (v < N_NODES) {
            degs[v] = deg[t];
            begs[v] = b * BIN_CAP + base[t];
        }
    }

    for (int i = t; i < m; i += 256) {
        unsigned k = buf[i];
        int p = atomicAdd(&cur[(k >> 14) & 127], 1);
        binbuf[(size_t)b * BIN_CAP + p] = k & 0x3FFFu;   // store src only
    }
}

// ---------------- per-layer kernels ----------------

// hl(bf16) = h(fp32) @ W + b  (fp32 math, W staged in LDS)
__global__ __launch_bounds__(256) void gemm_kernel(const float* __restrict__ h,
                                                   const float* __restrict__ W,
                                                   const float* __restrict__ bias,
                                                   __hip_bfloat16* __restrict__ hl) {
    __shared__ float Ws[D * D];
    __shared__ float bs_s[D];
    const float4* Wv = (const float4*)W;
    float4* Wsv = (float4*)Ws;
    for (int i = threadIdx.x; i < D * D / 4; i += 256) Wsv[i] = Wv[i];
    if (threadIdx.x < D) bs_s[threadIdx.x] = bias[threadIdx.x];
    __syncthreads();

    const int rg = threadIdx.x >> 4;
    const int cg = threadIdx.x & 15;
    const int row0 = blockIdx.x * 64 + rg * 4;
    const int col0 = cg * 8;

    float acc[4][8];
#pragma unroll
    for (int r = 0; r < 4; ++r)
#pragma unroll
        for (int c = 0; c < 8; ++c) acc[r][c] = 0.f;

    for (int k = 0; k < D; k += 4) {
        float a[4][4];
#pragma unroll
        for (int r = 0; r < 4; ++r) {
            int rr = row0 + r;
            if (rr > N_NODES - 1) rr = N_NODES - 1;
            float4 t = *(const float4*)(h + rr * D + k);
            a[r][0] = t.x; a[r][1] = t.y; a[r][2] = t.z; a[r][3] = t.w;
        }
#pragma unroll
        for (int kk = 0; kk < 4; ++kk) {
            float4 w0 = *(const float4*)(&Ws[(k + kk) * D + col0]);
            float4 w1 = *(const float4*)(&Ws[(k + kk) * D + col0 + 4]);
#pragma unroll
            for (int r = 0; r < 4; ++r) {
                float av = a[r][kk];
                acc[r][0] += av * w0.x; acc[r][1] += av * w0.y;
                acc[r][2] += av * w0.z; acc[r][3] += av * w0.w;
                acc[r][4] += av * w1.x; acc[r][5] += av * w1.y;
                acc[r][6] += av * w1.z; acc[r][7] += av * w1.w;
            }
        }
    }

#pragma unroll
    for (int r = 0; r < 4; ++r) {
        int rr = row0 + r;
        if (rr < N_NODES) {
            union { uint4 u; __hip_bfloat16 b[8]; } o;
#pragma unroll
            for (int c = 0; c < 8; ++c)
                o.b[c] = __float2bfloat16(acc[r][c] + bs_s[col0 + c]);
            *(uint4*)((unsigned short*)hl + rr * D + col0) = o.u;
        }
    }
}

__device__ __forceinline__ float bf_lo(unsigned u) {
    u <<= 16; return __builtin_bit_cast(float, u);
}
__device__ __forceinline__ float bf_hi(unsigned u) {
    u &= 0xffff0000u; return __builtin_bit_cast(float, u);
}

// out[v] = relu(hl[v] + sum_{in-edges} hl[src])
// One wave per node. Lane = (group g = lane>>4, chunk c = lane&15).
// Each gather instruction: 4 edges x 16 lanes x 16 B = 1 KB. Unroll 8 -> 32 edges in flight.
__global__ __launch_bounds__(256) void aggregate_kernel(const uint4* __restrict__ hlq,
                                                        const int* __restrict__ begs,
                                                        const int* __restrict__ degs,
                                                        const int* __restrict__ csr,
                                                        float* __restrict__ out) {
    int node = blockIdx.x * 4 + (threadIdx.x >> 6);
    if (node >= N_NODES) return;
    const int lane = threadIdx.x & 63;
    const int g = lane >> 4;     // edge slot within a gather
    const int c = lane & 15;     // 16-byte chunk within row (bf16 cols c*8..c*8+7)

    const int beg = begs[node];
    const int end = beg + degs[node];

    float a0, a1, a2, a3, a4, a5, a6, a7;
    if (g == 0) {   // self loop handled by group 0
        uint4 s = hlq[node * 16 + c];
        a0 = bf_lo(s.x); a1 = bf_hi(s.x);
        a2 = bf_lo(s.y); a3 = bf_hi(s.y);
        a4 = bf_lo(s.z); a5 = bf_hi(s.z);
        a6 = bf_lo(s.w); a7 = bf_hi(s.w);
    } else {
        a0 = a1 = a2 = a3 = a4 = a5 = a6 = a7 = 0.f;
    }

    for (int eb = beg; eb < end; eb += 32) {
#pragma unroll
        for (int j = 0; j < 8; ++j) {
            int e0 = eb + 4 * j;
            if (e0 < end) {                     // wave-uniform guard
                int e = e0 + g;
                int eu = (e < end) ? e : (end - 1);
                int u = csr[eu];
                uint4 v = hlq[u * 16 + c];
                if (e >= end) { v.x = 0u; v.y = 0u; v.z = 0u; v.w = 0u; }
                a0 += bf_lo(v.x); a1 += bf_hi(v.x);
                a2 += bf_lo(v.y); a3 += bf_hi(v.y);
                a4 += bf_lo(v.z); a5 += bf_hi(v.z);
                a6 += bf_lo(v.w); a7 += bf_hi(v.w);
            }
        }
    }

    // reduce the 4 groups (xor 16 then 32 sums all four)
    a0 += __shfl_xor(a0, 16); a1 += __shfl_xor(a1, 16);
    a2 += __shfl_xor(a2, 16); a3 += __shfl_xor(a3, 16);
    a4 += __shfl_xor(a4, 16); a5 += __shfl_xor(a5, 16);
    a6 += __shfl_xor(a6, 16); a7 += __shfl_xor(a7, 16);
    a0 += __shfl_xor(a0, 32); a1 += __shfl_xor(a1, 32);
    a2 += __shfl_xor(a2, 32); a3 += __shfl_xor(a3, 32);
    a4 += __shfl_xor(a4, 32); a5 += __shfl_xor(a5, 32);
    a6 += __shfl_xor(a6, 32); a7 += __shfl_xor(a7, 32);

    if (g == 0) {
        float4 o0, o1;
        o0.x = fmaxf(a0, 0.f); o0.y = fmaxf(a1, 0.f);
        o0.z = fmaxf(a2, 0.f); o0.w = fmaxf(a3, 0.f);
        o1.x = fmaxf(a4, 0.f); o1.y = fmaxf(a5, 0.f);
        o1.z = fmaxf(a6, 0.f); o1.w = fmaxf(a7, 0.f);
        float4* orow = (float4*)(out + (size_t)node * D);
        orow[c * 2]     = o0;
        orow[c * 2 + 1] = o1;
    }
}

// ---------------- launch ----------------

extern "C" void kernel_launch(void* const* d_in, const int* in_sizes, int n_in,
                              void* d_out, int out_size, void* d_ws, size_t ws_size,
                              hipStream_t stream) {
    const float* node_feats = (const float*)d_in[0];
    const int*   src        = (const int*)d_in[1];
    const int*   dst        = (const int*)d_in[2];
    const float* Ws         = (const float*)d_in[3];
    const float* bs         = (const float*)d_in[4];
    float* out = (float*)d_out;

    char* ws = (char*)d_ws;
    int*      binCursor = (int*)(ws + 0);          // 79 ints
    int*      begs      = (int*)(ws + 1024);       // 10240 ints -> ends 41984
    int*      degs      = (int*)(ws + 41984);      // 10240 ints -> ends 82944
    unsigned* binbuf    = (unsigned*)(ws + 82944); // 79*10240 u32 -> ends 3318784 (csr in place)
    __hip_bfloat16* hl  = (__hip_bfloat16*)(ws + 3318784); // 2.56 MB -> ends 5878784
    float*    bufA      = (float*)(ws + 5878784);  // 5.12 MB -> ends 10998784

    zero_small_kernel<<<1, 128, 0, stream>>>(binCursor, NBINS);
    binA_kernel<<<250, 256, 0, stream>>>(src, dst, binCursor, binbuf);
    binB_kernel<<<NBINS, 256, 0, stream>>>(binbuf, binCursor, begs, degs);

    const float* hin = node_feats;
    for (int l = 0; l < N_LAYERS; ++l) {
        gemm_kernel<<<(N_NODES + 63) / 64, 256, 0, stream>>>(
            hin, Ws + (size_t)l * D * D, bs + (size_t)l * D, hl);
        float* hout = (l % 2 == 0) ? bufA : out;
        aggregate_kernel<<<(N_NODES + 3) / 4, 256, 0, stream>>>(
            (const uint4*)hl, begs, degs, (const int*)binbuf, hout);
        hin = hout;
    }
}